// Round 10
// baseline (319.540 us; speedup 1.0000x reference)
//
#include <hip/hip_runtime.h>
#include <hip/hip_bf16.h>
#include <math.h>

// Problem constants
#define N_   16
#define A_   64
#define HW_  256
#define B_   32
#define C_   16
#define D_   16

// ws layout (floats) — ~52 MB
#define F_POSE  0u          // 2097152  POSEraw [b][s][n][pp]  (raw conv out, transposed)
#define F_WT    2097152u    // 2097152  WT [b][s][c*16+mj]
#define F_ACT   4194304u    // 131072   ACTraw [ch=b][n][s]    (raw conv out)
#define F_PART  4325376u    // 8650752  Part[1024][33][256]
#define F_RED   12976128u   // 135168   Red16[16][33][256]
#define F_STATP 13111296u   // 1024     per-(b,n) pose sum/sumsq
#define F_STATA 13112320u   // 1024     per-(ch,n) act sum/sumsq

__device__ __forceinline__ float digamma_f(float x){
    // valid for x >= ~1 (all call sites); shift to x>=8 then asymptotic
    float r = 0.f;
    while (x < 8.f){ r -= 1.f/x; x += 1.f; }
    float inv = 1.f/x, inv2 = inv*inv;
    float p = logf(x) - 0.5f*inv
            - inv2*(0.08333333333333333f - inv2*(0.008333333333333333f - inv2*0.003968253968253968f));
    return r + p;
}

__device__ __forceinline__ float sigmoid_f(float x){ return 1.f/(1.f+__expf(-x)); }

// ---------------- K1: conv 1x1 (raw, transposed out, + BN stat partials) fused with W transpose ----
// blocks 0..543: conv (g = blk%34, n = blk/34); blocks 544..1055: W transpose.
__global__ __launch_bounds__(256) void k_main(const float* __restrict__ x,
    const float* __restrict__ pw, const float* __restrict__ W,
    float* __restrict__ POSEraw, float* __restrict__ ACTraw, float* __restrict__ WTo,
    float* __restrict__ StatP, float* __restrict__ StatA)
{
    __shared__ float sh[4096];
    const int blk = blockIdx.x;
    const int t = threadIdx.x;
    if (blk < 544){
        const int g = blk % 34, n = blk / 34;
        float* swl = sh;                 // 1024 floats of weights
        ((float4*)swl)[t] = ((const float4*)(pw + (size_t)g*1024))[t];
        __syncthreads();
        const float* xp = x + (size_t)n*16384 + t;
        float acc[16];
#pragma unroll
        for (int i=0;i<16;i++) acc[i]=0.f;
#pragma unroll 4
        for (int a=0;a<A_;a++){
            float xv = xp[(size_t)a*256];
#pragma unroll
            for (int oo=0;oo<16;oo++) acc[oo] = fmaf(xv, swl[oo*64+a], acc[oo]);
        }
        if (g < 32){
            // raw transposed store: POSEraw[b][s][n][pp]
            float* dst = POSEraw + (size_t)g*65536 + (size_t)t*256 + n*16;
#pragma unroll
            for (int i=0;i<4;i++){
                float4 v; v.x=acc[i*4+0]; v.y=acc[i*4+1]; v.z=acc[i*4+2]; v.w=acc[i*4+3];
                *(float4*)(dst + i*4) = v;
            }
            // per-(b,n) partial stats over 16 pp x 256 sites
            float sp=0.f, sq=0.f;
#pragma unroll
            for (int oo=0;oo<16;oo++){ sp += acc[oo]; sq = fmaf(acc[oo], acc[oo], sq); }
#pragma unroll
            for (int off=32; off>=1; off>>=1){
                sp += __shfl_xor(sp, off, 64);
                sq += __shfl_xor(sq, off, 64);
            }
            float* red = sh + 1024;
            if ((t&63)==0){ red[t>>6]=sp; red[4+(t>>6)]=sq; }
            __syncthreads();
            if (t==0){
                StatP[(size_t)(g*16+n)*2  ] = red[0]+red[1]+red[2]+red[3];
                StatP[(size_t)(g*16+n)*2+1] = red[4]+red[5]+red[6]+red[7];
            }
        } else {
            // raw act store: ACTraw[ch][n][s]
#pragma unroll
            for (int oo=0;oo<16;oo++){
                const int ch = (g-32)*16 + oo;
                ACTraw[(size_t)ch*4096 + (size_t)n*256 + t] = acc[oo];
            }
            // per-(ch,n) partial stats over 256 sites
            float* ared = sh + 1024;     // [16 ch][8]
            const int wid = t>>6;
#pragma unroll
            for (int oo=0;oo<16;oo++){
                float s = acc[oo], q = acc[oo]*acc[oo];
#pragma unroll
                for (int off=32; off>=1; off>>=1){
                    s += __shfl_xor(s, off, 64);
                    q += __shfl_xor(q, off, 64);
                }
                if ((t&63)==0){ ared[oo*8+wid]=s; ared[oo*8+4+wid]=q; }
            }
            __syncthreads();
            if (t<16){
                const int ch = (g-32)*16 + t;
                StatA[(size_t)(ch*16+n)*2  ] = ared[t*8+0]+ared[t*8+1]+ared[t*8+2]+ared[t*8+3];
                StatA[(size_t)(ch*16+n)*2+1] = ared[t*8+4]+ared[t*8+5]+ared[t*8+6]+ared[t*8+7];
            }
        }
    } else {
        // W transpose: [b][cmj][s] -> [b][s][cmj]
        const int q = blk - 544;
        const int b = q & 31, chunk = q >> 5;
        const int s0 = chunk*16;
        float* lw = sh;                  // 4096 floats
        const float* src = W + ((size_t)b*256 + t)*256 + s0;
        float4 v0 = ((const float4*)src)[0];
        float4 v1 = ((const float4*)src)[1];
        float4 v2 = ((const float4*)src)[2];
        float4 v3 = ((const float4*)src)[3];
        lw[ 0*256+t]=v0.x; lw[ 1*256+t]=v0.y; lw[ 2*256+t]=v0.z; lw[ 3*256+t]=v0.w;
        lw[ 4*256+t]=v1.x; lw[ 5*256+t]=v1.y; lw[ 6*256+t]=v1.z; lw[ 7*256+t]=v1.w;
        lw[ 8*256+t]=v2.x; lw[ 9*256+t]=v2.y; lw[10*256+t]=v2.z; lw[11*256+t]=v2.w;
        lw[12*256+t]=v3.x; lw[13*256+t]=v3.y; lw[14*256+t]=v3.z; lw[15*256+t]=v3.w;
        __syncthreads();
        float* dst = WTo + ((size_t)b*256 + s0)*256;
#pragma unroll
        for (int j=0;j<4;j++){
            int flat = j*1024 + t*4;
            *(float4*)(dst + flat) = *(const float4*)(lw + flat);
        }
    }
}

// ---------------- pass: BN-fold + E-step + moments; derive inlined (it>0) ----------------
// grid 1024 = (b, chunk8); 256 threads = (n,c) = cell t. 8 sites per block.
template<int FIRST>
__global__ __launch_bounds__(256) void k_pass(const float* __restrict__ POSEraw,
    const float* __restrict__ ACTraw, const float* __restrict__ WT,
    const float* __restrict__ StatP, const float* __restrict__ StatA,
    const float* __restrict__ gp, const float* __restrict__ bp,
    const float* __restrict__ ga, const float* __restrict__ bb,
    const float* __restrict__ Red16, float* __restrict__ Part)
{
    const int wg = blockIdx.x;
    const int chunk = wg & 31, b = wg >> 5;   // 32 chunks of 8 sites
    const int s0 = chunk*8;
    const int t = threadIdx.x;
    const int n = t>>4, c = t&15;
    __shared__ float shP[2560];   // [si<8][n][pad20]  BN-applied poses
    __shared__ float shW[2560];   // [si<8][c][pad20]
    __shared__ float shA[128];    // [si*16+n]         sigmoided acts
    __shared__ float shBN[4];     // {pose sc, pose sh, act sc, act sh} for this b

    // ---- phase A: stage W + compute this block's BN params ----
    {
        const float* wsrc = WT + ((size_t)b*256 + s0)*256;
#pragma unroll
        for (int j=0;j<2;j++){
            int flat = j*1024 + t*4;
            int si = flat>>8, rm = flat&255;
            int nn = rm>>4, p0 = rm&15;
            *(float4*)(shW + si*320 + nn*20 + p0) = *(const float4*)(wsrc+flat);
        }
        if (t < 32){
            const bool isP = (t < 16);
            const int lane = t & 15;
            float S, Q;
            if (isP){ S = StatP[(size_t)(b*16+lane)*2]; Q = StatP[(size_t)(b*16+lane)*2+1]; }
            else    { S = StatA[(size_t)(b*16+lane)*2]; Q = StatA[(size_t)(b*16+lane)*2+1]; }
#pragma unroll
            for (int off=8; off>=1; off>>=1){
                S += __shfl_xor(S, off, 16);
                Q += __shfl_xor(Q, off, 16);
            }
            if (lane == 0){
                if (isP){
                    float mean = S*(1.f/65536.f), var = Q*(1.f/65536.f) - mean*mean;
                    float sc = gp[b]*rsqrtf(var + 1e-5f);
                    shBN[0] = sc; shBN[1] = bp[b] - mean*sc;
                } else {
                    float mean = S*(1.f/4096.f), var = Q*(1.f/4096.f) - mean*mean;
                    float sc = ga[b]*rsqrtf(var + 1e-5f);
                    shBN[2] = sc; shBN[3] = bb[b] - mean*sc;
                }
            }
        }
    }
    __syncthreads();

    // ---- phase B: stage POSE with BN + ACT with BN+sigmoid ----
    {
        const float sc = shBN[0], shf = shBN[1];
        const float* psrc = POSEraw + ((size_t)b*256 + s0)*256;
#pragma unroll
        for (int j=0;j<2;j++){
            int flat = j*1024 + t*4;
            int si = flat>>8, rm = flat&255;
            int nn = rm>>4, p0 = rm&15;
            float4 v = *(const float4*)(psrc+flat);
            v.x = fmaf(v.x, sc, shf); v.y = fmaf(v.y, sc, shf);
            v.z = fmaf(v.z, sc, shf); v.w = fmaf(v.w, sc, shf);
            *(float4*)(shP + si*320 + nn*20 + p0) = v;
        }
        if (t < 32){
            const float sa = shBN[2], ha = shBN[3];
            int nn = t>>1, s4 = (t&1)*4;
            float4 v = *(const float4*)(ACTraw + (size_t)b*4096 + nn*256 + s0 + s4);
            shA[(s4+0)*16+nn] = sigmoid_f(fmaf(v.x,sa,ha));
            shA[(s4+1)*16+nn] = sigmoid_f(fmaf(v.y,sa,ha));
            shA[(s4+2)*16+nn] = sigmoid_f(fmaf(v.z,sa,ha));
            shA[(s4+3)*16+nn] = sigmoid_f(fmaf(v.w,sa,ha));
        }
    }

    // ---- inline derive of this thread's (n,c) cell: 16-way fold of Red16 ----
    float mj[16], ip[16], basev=0.f, nuv=0.f;
    if (!FIRST){
        const float* rp = Red16 + t;
        float Rj = 0.f;
#pragma unroll
        for (int q=0;q<16;q++) Rj += rp[(size_t)(q*33)*256];
        float kap = 1.f + Rj;
        nuv = 17.f + Rj;
        float ik  = 1.f/kap;
        float El  = 11.090354888959125f;   // D*ln2
#pragma unroll
        for (int d=0; d<16; d++){
            float S1 = 0.f, S2 = 0.f;
#pragma unroll
            for (int q=0;q<16;q++){
                S1 += rp[(size_t)(q*33+1+d)*256];
                S2 += rp[(size_t)(q*33+17+d)*256];
            }
            mj[d] = S1*ik;
            float iPsi = 1.f + S2 - S1*S1*ik;
            ip[d] = 1.f/iPsi;
            El -= logf(iPsi);
        }
#pragma unroll
        for (int d=0; d<16; d++) El += digamma_f(0.5f*(nuv - (float)d));
        float asum = kap;
#pragma unroll
        for (int off=8; off>=1; off>>=1) asum += __shfl_xor(asum, off, 16);
        float Epi = digamma_f(kap) - digamma_f(asum);
        basev = Epi + 0.5f*El - 14.703016531274762f - 8.f*ik;
    }
    __syncthreads();

    float racc=0.f, s1[16], s2[16];
#pragma unroll
    for (int d=0;d<16;d++){ s1[d]=0.f; s2[d]=0.f; }

#pragma unroll 2
    for (int si=0; si<8; ++si){
        float P[16], Wv[16];
        const float* pb = shP + si*320 + n*20;
        const float* wb = shW + si*320 + c*20;
#pragma unroll
        for (int i=0;i<16;i+=4){
            float4 v = *(const float4*)(pb+i);
            P[i]=v.x; P[i+1]=v.y; P[i+2]=v.z; P[i+3]=v.w;
            float4 u = *(const float4*)(wb+i);
            Wv[i]=u.x; Wv[i+1]=u.y; Wv[i+2]=u.z; Wv[i+3]=u.w;
        }
        float V[16];
#pragma unroll
        for (int a=0;a<4;a++){
#pragma unroll
            for (int j=0;j<4;j++){
                float acc = P[a*4+0]*Wv[0*4+j];
                acc = fmaf(P[a*4+1], Wv[1*4+j], acc);
                acc = fmaf(P[a*4+2], Wv[2*4+j], acc);
                acc = fmaf(P[a*4+3], Wv[3*4+j], acc);
                V[a*4+j] = acc;
            }
        }
        const float av = shA[si*16+n];
        float r;
        if (FIRST){
            r = 0.0625f * av;
        } else {
            // two-chain distance accumulation (halves dependent-FMA latency)
            float q0 = 0.f, q1 = 0.f;
#pragma unroll
            for (int d=0;d<16;d+=2){
                float dv0 = V[d]-mj[d];
                float dv1 = V[d+1]-mj[d+1];
                q0 = fmaf(dv0*ip[d],   dv0, q0);
                q1 = fmaf(dv1*ip[d+1], dv1, q1);
            }
            float arg = fmaf(-0.5f*nuv, q0+q1, basev);
            float mx = arg;
#pragma unroll
            for (int off=8; off>=1; off>>=1) mx = fmaxf(mx, __shfl_xor(mx, off, 64));
            float e = __expf(arg-mx);
            float ssum = e;
#pragma unroll
            for (int off=8; off>=1; off>>=1) ssum += __shfl_xor(ssum, off, 64);
            r = (e/ssum)*av;
        }
        racc += r;
#pragma unroll
        for (int d=0;d<16;d++){
            s1[d] = fmaf(r, V[d], s1[d]);
            s2[d] = fmaf(r*V[d], V[d], s2[d]);
        }
    }

    float* pp = Part + (size_t)wg*33*256 + t;
    pp[0] = racc;
#pragma unroll
    for (int d=0;d<16;d++){
        pp[(size_t)(1+d)*256]  = s1[d];
        pp[(size_t)(17+d)*256] = s2[d];
    }
}

// ---------------- reduce: 1024 partials -> Red16[16][33][256] (528 blocks) ----------------
__global__ __launch_bounds__(256) void k_red(const float* __restrict__ Part,
    float* __restrict__ Red16)
{
    const int k = blockIdx.x;   // 0..32
    const int q = blockIdx.y;   // 0..15
    const int t = threadIdx.x;
    const float* src = Part + (size_t)q*64*8448 + (size_t)k*256 + t;
    float a0=0,a1=0,a2=0,a3=0,a4=0,a5=0,a6=0,a7=0;
#pragma unroll
    for (int i=0;i<64;i+=8){
        a0 += src[(size_t)(i+0)*8448];
        a1 += src[(size_t)(i+1)*8448];
        a2 += src[(size_t)(i+2)*8448];
        a3 += src[(size_t)(i+3)*8448];
        a4 += src[(size_t)(i+4)*8448];
        a5 += src[(size_t)(i+5)*8448];
        a6 += src[(size_t)(i+6)*8448];
        a7 += src[(size_t)(i+7)*8448];
    }
    Red16[((size_t)q*33 + k)*256 + t] = ((a0+a1)+(a2+a3)) + ((a4+a5)+(a6+a7));
}

// ---------------- final: in-block derive (16-fold) + BN(m) per c + BN(a)+sigmoid ----------------
__global__ __launch_bounds__(256) void k_final(const float* __restrict__ Red16,
    const float* __restrict__ bu, const float* __restrict__ ba,
    float* __restrict__ out)
{
    const int c = blockIdx.x;
    const int t = threadIdx.x;
    __shared__ float shMj[256];   // [n][d]
    __shared__ float shEp[16], shEl[16];
    __shared__ float red[8];

    if (t < 16){
        const int cell = t*16 + c;   // (n=t, c)
        const float* rp = Red16 + cell;
        float Rj = 0.f;
#pragma unroll
        for (int q=0;q<16;q++) Rj += rp[(size_t)(q*33)*256];
        float kap = 1.f + Rj;
        float nuv = 17.f + Rj;
        float ik  = 1.f/kap;
        float El  = 11.090354888959125f;
#pragma unroll
        for (int d=0; d<16; d++){
            float S1 = 0.f, S2 = 0.f;
#pragma unroll
            for (int q=0;q<16;q++){
                S1 += rp[(size_t)(q*33+1+d)*256];
                S2 += rp[(size_t)(q*33+17+d)*256];
            }
            shMj[t*16+d] = S1*ik;
            float iPsi = 1.f + S2 - S1*S1*ik;
            El -= logf(iPsi);
        }
#pragma unroll
        for (int d=0; d<16; d++) El += digamma_f(0.5f*(nuv - (float)d));
        float asum = 16.f;
        for (int cc=0; cc<16; cc++){
#pragma unroll
            for (int q=0;q<16;q++) asum += Red16[(size_t)(q*33)*256 + t*16+cc];
        }
        shEp[t] = digamma_f(kap) - digamma_f(asum);
        shEl[t] = El;
    }
    __syncthreads();

    const int n = t>>4, d = t&15;
    float mv = shMj[n*16+d];
    float s = mv, q = mv*mv;
#pragma unroll
    for (int off=32; off>=1; off>>=1){
        s += __shfl_xor(s, off, 64);
        q += __shfl_xor(q, off, 64);
    }
    if ((t&63)==0){ red[t>>6]=s; red[4+(t>>6)]=q; }
    __syncthreads();
    float S = red[0]+red[1]+red[2]+red[3];
    float Q = red[4]+red[5]+red[6]+red[7];
    float mean = S*(1.f/256.f);
    float var  = Q*(1.f/256.f) - mean*mean;
    float rs   = rsqrtf(var + 1e-5f);
    out[256 + (size_t)(n*16+c)*16 + d] = (mv-mean)*rs;

    if (t < 16){
        const int nn = t;
        float Ep = shEp[nn], El = shEl[nn];
        float Hq = 22.703016531274762f - 0.5f*El;   // 0.5*D*ln(2*pi*e) - 0.5*Elnlam
        float araw = ba[c] - (expf(Ep)*Hq + bu[c]);
        float as = araw, aq = araw*araw;
        // reduce over 16 n-lanes: width 16 so off=8 exchanges halves (R5 fix)
#pragma unroll
        for (int off=8; off>=1; off>>=1){
            as += __shfl_xor(as, off, 16);
            aq += __shfl_xor(aq, off, 16);
        }
        float am  = as*(1.f/16.f);
        float av  = aq*(1.f/16.f) - am*am;
        float ars = rsqrtf(av + 1e-5f);
        float z = (araw-am)*ars;
        out[nn*16+c] = 1.f/(1.f+expf(-z));
    }
}

extern "C" void kernel_launch(void* const* d_in, const int* in_sizes, int n_in,
                              void* d_out, int out_size, void* d_ws, size_t ws_size,
                              hipStream_t stream)
{
    const float* x   = (const float*)d_in[0];
    const float* pw  = (const float*)d_in[1];
    const float* gp  = (const float*)d_in[2];
    const float* bp  = (const float*)d_in[3];
    const float* ga  = (const float*)d_in[4];
    const float* bb  = (const float*)d_in[5];
    const float* Wij = (const float*)d_in[6];
    const float* bu  = (const float*)d_in[7];
    const float* ba  = (const float*)d_in[8];
    float* out = (float*)d_out;
    float* ws  = (float*)d_ws;

    float* POSEraw = ws + F_POSE;
    float* WT      = ws + F_WT;
    float* ACTraw  = ws + F_ACT;
    float* Part    = ws + F_PART;
    float* Red16   = ws + F_RED;
    float* StatP   = ws + F_STATP;
    float* StatA   = ws + F_STATA;

    k_main<<<1056, 256, 0, stream>>>(x, pw, Wij, POSEraw, ACTraw, WT, StatP, StatA);

    k_pass<1><<<1024, 256, 0, stream>>>(POSEraw, ACTraw, WT, StatP, StatA, gp, bp, ga, bb, Red16, Part);
    k_red<<<dim3(33,16), 256, 0, stream>>>(Part, Red16);
    k_pass<0><<<1024, 256, 0, stream>>>(POSEraw, ACTraw, WT, StatP, StatA, gp, bp, ga, bb, Red16, Part);
    k_red<<<dim3(33,16), 256, 0, stream>>>(Part, Red16);
    k_pass<0><<<1024, 256, 0, stream>>>(POSEraw, ACTraw, WT, StatP, StatA, gp, bp, ga, bb, Red16, Part);
    k_red<<<dim3(33,16), 256, 0, stream>>>(Part, Red16);

    k_final<<<16, 256, 0, stream>>>(Red16, bu, ba, out);
}